// Round 5
// baseline (5689.288 us; speedup 1.0000x reference)
//
#include <hip/hip_runtime.h>
#include <stdint.h>

// LSTM autoencoder: B=64, T=256, P=128, H=512, LAT=128
// out = [x_hat (64*256*128 f32), z (64*128 f32)]

typedef unsigned short u16;
typedef unsigned int u32;
typedef float f32x4 __attribute__((ext_vector_type(4)));
typedef __bf16 bf16x8 __attribute__((ext_vector_type(8)));
typedef unsigned int u32x4 __attribute__((ext_vector_type(4)));

#define AT_LD(p) __hip_atomic_load((p), __ATOMIC_RELAXED, __HIP_MEMORY_SCOPE_AGENT)
#define AT_ST(p, v) __hip_atomic_store((p), (v), __ATOMIC_RELAXED, __HIP_MEMORY_SCOPE_AGENT)

__device__ __forceinline__ u16 f2bf(float f) {
  u32 u = __builtin_bit_cast(u32, f);
  u += 0x7FFFu + ((u >> 16) & 1u);
  return (u16)(u >> 16);
}
__device__ __forceinline__ float bf2f(u16 h) {
  return __builtin_bit_cast(float, (u32)h << 16);
}
__device__ __forceinline__ bf16x8 ld8(const u16* p) {
  u32x4 v = *(const u32x4*)p;
  return __builtin_bit_cast(bf16x8, v);
}
__device__ __forceinline__ float sigf(float x) { return 1.f / (1.f + __expf(-x)); }
__device__ __forceinline__ float tanhx(float x) {
  x = fminf(fmaxf(x, -15.f), 15.f);
  float e = __expf(2.f * x);
  return (e - 1.f) / (e + 1.f);
}

// ---- prep kernels ----
__global__ void k_prep_x(const float* __restrict__ x, const float* __restrict__ st,
                         u16* __restrict__ Ax, u16* __restrict__ Axs, int n) {
  int i = blockIdx.x * 256 + threadIdx.x;
  if (i >= n) return;
  Ax[i] = f2bf(x[i]);
  int col = i & 127;
  int t = (i >> 7) & 255;
  float v = (t == 0) ? st[col] : x[i - 128];
  Axs[i] = f2bf(v);
}

// merged f32->bf16 conversions (13 jobs, prefix table)
struct CvtJobs {
  const float* src[13];
  u16* dst[13];
  int off[14];  // off[0]=0 .. off[13]=total
};
__global__ void k_cvt_all(CvtJobs j, int total) {
  int i = blockIdx.x * 256 + threadIdx.x;
  if (i >= total) return;
  int a = 0;
#pragma unroll
  for (int k = 1; k < 13; ++k) a += (i >= j.off[k]) ? 1 : 0;
  int local = i - j.off[a];
  j.dst[a][local] = f2bf(j.src[a][local]);
}

// ---- bulk GEMM: C[M][N] = A[M][K] @ B'[N][K]^T + bias, bf16 in, fp32 acc ----
__global__ __launch_bounds__(256) void k_gemm_bt(
    const u16* __restrict__ A, const u16* __restrict__ B, const float* __restrict__ bias,
    u16* __restrict__ Cb, float* __restrict__ Cf, int M, int N, int K, int sig) {
  __shared__ __align__(16) u16 As[128 * 64];
  __shared__ __align__(16) u16 Bs[128 * 64];
  const int m0 = blockIdx.x * 128, n0 = blockIdx.y * 128;
  const int tid = threadIdx.x, lane = tid & 63, wave = tid >> 6;
  const int wm = wave >> 1, wn = wave & 1;

  f32x4 acc[4][4];
#pragma unroll
  for (int i = 0; i < 4; ++i)
#pragma unroll
    for (int j = 0; j < 4; ++j) acc[i][j] = (f32x4){0.f, 0.f, 0.f, 0.f};

  const int nkt = K >> 6;
  for (int kt = 0; kt < nkt; ++kt) {
#pragma unroll
    for (int i = 0; i < 4; ++i) {
      int ch = tid + (i << 8);
      int row = ch >> 3, k8 = ch & 7;
      int dst = row * 128 + ((k8 * 16) ^ ((row & 7) << 4));
      u32x4 va = *(const u32x4*)(A + (size_t)(m0 + row) * K + kt * 64 + k8 * 8);
      *(u32x4*)((char*)As + dst) = va;
      u32x4 vb = *(const u32x4*)(B + (size_t)(n0 + row) * K + kt * 64 + k8 * 8);
      *(u32x4*)((char*)Bs + dst) = vb;
    }
    __syncthreads();
#pragma unroll
    for (int kk = 0; kk < 2; ++kk) {
      int kb = kk * 64 + ((lane >> 4) << 4);
      bf16x8 afr[4], bfr[4];
#pragma unroll
      for (int i = 0; i < 4; ++i) {
        int ra = wm * 64 + i * 16 + (lane & 15);
        afr[i] = ld8((const u16*)((const char*)As + ra * 128 + (kb ^ ((ra & 7) << 4))));
        int rb = wn * 64 + i * 16 + (lane & 15);
        bfr[i] = ld8((const u16*)((const char*)Bs + rb * 128 + (kb ^ ((rb & 7) << 4))));
      }
#pragma unroll
      for (int i = 0; i < 4; ++i)
#pragma unroll
        for (int j = 0; j < 4; ++j)
          acc[i][j] = __builtin_amdgcn_mfma_f32_16x16x32_bf16(afr[i], bfr[j], acc[i][j], 0, 0, 0);
    }
    __syncthreads();
  }
#pragma unroll
  for (int i = 0; i < 4; ++i) {
#pragma unroll
    for (int j = 0; j < 4; ++j) {
      int col = n0 + wn * 64 + j * 16 + (lane & 15);
      float bv = bias ? bias[col] : 0.f;
#pragma unroll
      for (int r = 0; r < 4; ++r) {
        int row = m0 + wm * 64 + i * 16 + ((lane >> 4) << 2) + r;
        float v = acc[i][j][r] + bv;
        if (sig) Cf[(size_t)row * N + col] = 1.f / (1.f + __expf(-v));
        else     Cb[(size_t)row * N + col] = f2bf(v);
      }
    }
  }
}

// ---- persistent recurrent LSTM kernel, wave-local gates ----
// 8 chains x 32 col-blocks (16 h-cols each). chain = bid&7, c = bid>>3.
// Wlds n-layout: n = hcol*4 + gate  (one wave owns 4 hcols x all 4 gates).
// After MFMA: in-register quad transpose -> each lane has i,f,g,o of one cell;
// c-state in VGPR; per-wave publish + own-vmcnt drain + per-wave tag (128/chain).
// Only 2 __syncthreads per step. Wlds bank-swizzled by n^(k8&3).
struct Rec3 {
  const u16* xW[8];      // precomputed x-projection (incl bias); null if fused
  const u16* Whh[8];     // bf16 [2048][512]
  const u16* Wih[8];     // bf16 [2048][512], fused only
  const float* bias[8];  // fused only
  const float* h0[8];    // fp32 [64][512] or null
  u16* seq[8];           // bf16 seq out or null
  float* hfin[8];
  u16* hxc[8];           // exchange base per chain
  int prod[8];           // producer chain (fused)
  int seqstride[8]; int coloff[8]; int rev[8]; int hfinstride[8];
  int grp[8]; int fused[8]; int fullp[8];
  u32* tags;             // [chain][128] u32 (c*4 + wave)
};

__global__ __launch_bounds__(256, 1) void k_rec3(Rec3 p) {
  const int chain = blockIdx.x & 7;
  const int c = blockIdx.x >> 3;  // 0..31
  const int tid = threadIdx.x, lane = tid & 63, wave = tid >> 6;
  const int arow = lane & 15, kg = lane >> 4;
  const int g4 = arow & 3;        // quad pos == gate (pre-transpose)
  const int h4 = arow >> 2;       // hcol within wave (0..3)
  const int myrow = (kg << 2) + g4;       // owned batch row (0..15)
  const int mycol = (wave << 2) + h4;     // owned hcol block-local (0..15)

  const u16* __restrict__ xW = p.xW[chain];
  const u16* __restrict__ Whh = p.Whh[chain];
  const u16* __restrict__ Wih = p.Wih[chain];
  const float* __restrict__ bias = p.bias[chain];
  const float* __restrict__ h0 = p.h0[chain];
  u16* seq = p.seq[chain];
  float* hfin = p.hfin[chain];
  u32* hx = (u32*)p.hxc[chain];
  const u32* hxp = (const u32*)p.hxc[p.prod[chain]];
  const int grp = p.grp[chain], rev = p.rev[chain];
  const int fused = p.fused[chain], fullp = p.fullp[chain];
  const int sstride = p.seqstride[chain], coloff = p.coloff[chain];
  const int hstride = p.hfinstride[chain];
  u32* myt = p.tags + chain * 128;
  const u32* pt = p.tags + p.prod[chain] * 128;

  __shared__ __align__(16) u16 Wlds[64][64][8];  // [k8][n^(k8&3)][k&7], n=hcol*4+gate
  __shared__ __align__(16) u16 Xlds[64][64][8];
  __shared__ __align__(16) u16 hbufA[8192];      // 16 rows x 512 cols, XOR-swizzled
  __shared__ float bbuf[64];

  // weight fills (n = hcol*4+gate, bank-swizzled)
  for (int e = tid; e < 4096; e += 256) {
    int n = e >> 6, k8 = e & 63;
    int grow = ((n & 3) << 9) + (c << 4) + (n >> 2);
    int ns = n ^ (k8 & 3);
    *(u32x4*)(&Wlds[k8][ns][0]) = *(const u32x4*)(Whh + (size_t)grow * 512 + k8 * 8);
    if (fused)
      *(u32x4*)(&Xlds[k8][ns][0]) = *(const u32x4*)(Wih + (size_t)grow * 512 + k8 * 8);
  }
  if (tid < 64) bbuf[tid] = fused ? bias[((tid & 3) << 9) + (c << 4) + (tid >> 2)] : 0.f;

  float creg = 0.f;  // c-state: one cell per lane, in register

  // publish h_0 slice (slot 0): pack col pairs via shfl, even-h lanes store u32
  {
    float hv = h0 ? h0[(size_t)(grp * 16 + myrow) * 512 + (c << 4) + mycol] : 0.f;
    u32 mypk = (u32)f2bf(hv);
    u32 part = (u32)__shfl_xor((int)mypk, 4);
    if ((h4 & 1) == 0)
      AT_ST(hx + ((size_t)0 * 32 + c) * 128 + (myrow << 3) + (mycol >> 1), mypk | (part << 16));
  }
  asm volatile("s_waitcnt vmcnt(0)" ::: "memory");
  if (lane == 0) AT_ST(myt + c * 4 + wave, 1u);
  __syncthreads();

  for (int t = 0; t < 256; ++t) {
    const int t_eff = rev ? 255 - t : t;
    const int slot = fullp ? t : (t & 3);
    const int slotn = fullp ? (t + 1) : ((t + 1) & 3);

    // xW prefetch (gate g4, rows kg*4+r): latency hides under the poll
    float xwv[4] = {0.f, 0.f, 0.f, 0.f};
    if (!fused) {
#pragma unroll
      for (int r = 0; r < 4; ++r) {
        int row = (kg << 2) + r;
        xwv[r] = bf2f(xW[((size_t)((grp * 16 + row) * 256 + t_eff)) * 2048 +
                         (g4 << 9) + (c << 4) + mycol]);
      }
    }
    // poll: wave 0 only, 2 own tags (+2 producer) per lane, s_sleep backoff
    if (wave == 0) {
      u32 to = (u32)(t + 1), tp = (u32)(t + 2);
      while (true) {
        int ok = (AT_LD(myt + lane) >= to) & (AT_LD(myt + 64 + lane) >= to);
        if (fused) ok &= (AT_LD(pt + lane) >= tp) & (AT_LD(pt + 64 + lane) >= tp);
        if (__all(ok)) break;
        __builtin_amdgcn_s_sleep(1);
      }
    }
    __syncthreads();  // #1: release + hbufA safe to overwrite

    // stage own-chain h_t into LDS (cooperative, swizzled)
#pragma unroll
    for (int i = 0; i < 4; ++i) {
      int cid = tid + (i << 8);
      int row = cid >> 6, ch8 = cid & 63;
      const u32* src = hx + ((size_t)slot * 32 + (ch8 >> 1)) * 128 +
                       (row << 3) + ((ch8 & 1) << 2);
      u32x4 v;
      v.x = AT_LD(src + 0); v.y = AT_LD(src + 1);
      v.z = AT_LD(src + 2); v.w = AT_LD(src + 3);
      *(u32x4*)((char*)hbufA + row * 1024 + ((ch8 << 4) ^ ((row & 7) << 4))) = v;
    }
    // fused: producer h_{t+1} fragments direct (regs)
    bf16x8 xf[16];
    if (fused) {
#pragma unroll
      for (int kt = 0; kt < 16; ++kt) {
        const u32* hp = hxp + ((size_t)(t + 1) * 32 + 2 * kt + (kg >> 1)) * 128 +
                        (arow << 3) + ((kg & 1) << 2);
        u32x4 v;
        v.x = AT_LD(hp + 0); v.y = AT_LD(hp + 1);
        v.z = AT_LD(hp + 2); v.w = AT_LD(hp + 3);
        xf[kt] = __builtin_bit_cast(bf16x8, v);
      }
    }
    __syncthreads();  // #2: hbufA visible

    // A-fragments + MFMA (split even/odd accumulators)
    bf16x8 af[16];
#pragma unroll
    for (int kt = 0; kt < 16; ++kt)
      af[kt] = ld8((const u16*)((const char*)hbufA + arow * 1024 +
                                ((kt * 64 + (kg << 4)) ^ ((arow & 7) << 4))));
    f32x4 ae = {0.f, 0.f, 0.f, 0.f}, ao = {0.f, 0.f, 0.f, 0.f};
    const int nswz = (wave << 4) + arow;
#pragma unroll
    for (int kt = 0; kt < 16; ++kt) {
      bf16x8 bw = ld8(&Wlds[(kt << 2) + kg][nswz ^ kg][0]);
      if (kt & 1) ao = __builtin_amdgcn_mfma_f32_16x16x32_bf16(af[kt], bw, ao, 0, 0, 0);
      else        ae = __builtin_amdgcn_mfma_f32_16x16x32_bf16(af[kt], bw, ae, 0, 0, 0);
      if (fused) {
        bf16x8 bx = ld8(&Xlds[(kt << 2) + kg][nswz ^ kg][0]);
        if (kt & 1) ae = __builtin_amdgcn_mfma_f32_16x16x32_bf16(xf[kt], bx, ae, 0, 0, 0);
        else        ao = __builtin_amdgcn_mfma_f32_16x16x32_bf16(xf[kt], bx, ao, 0, 0, 0);
      }
    }
    float bb = bbuf[nswz];
    float a0 = ae[0] + ao[0] + xwv[0] + bb;
    float a1 = ae[1] + ao[1] + xwv[1] + bb;
    float a2 = ae[2] + ao[2] + xwv[2] + bb;
    float a3 = ae[3] + ao[3] + xwv[3] + bb;

    // quad 4x4 transpose: lane quad-pos j ends with gates i,f,g,o of row kg*4+j
    float b0, b1, b2, b3;
    {
      float s0 = __shfl_xor(a0, 1), s1 = __shfl_xor(a1, 1);
      float s2 = __shfl_xor(a2, 1), s3 = __shfl_xor(a3, 1);
      bool j0 = (lane & 1) != 0;
      b0 = j0 ? s1 : a0;
      b1 = j0 ? a1 : s0;
      b2 = j0 ? s3 : a2;
      b3 = j0 ? a3 : s2;
    }
    float iv, fv, gv, ov;
    {
      float u0 = __shfl_xor(b0, 2), u1 = __shfl_xor(b1, 2);
      float u2 = __shfl_xor(b2, 2), u3 = __shfl_xor(b3, 2);
      bool j1 = (lane & 2) != 0;
      iv = j1 ? u2 : b0;
      fv = j1 ? u3 : b1;
      gv = j1 ? b2 : u0;
      ov = j1 ? b3 : u1;
    }
    float cc = sigf(fv) * creg + sigf(iv) * tanhx(gv);
    creg = cc;
    float hh = sigf(ov) * tanhx(cc);

    // publish (pack col pairs), per-wave drain, per-wave tag; bulk after tag
    u32 mypk = (u32)f2bf(hh);
    u32 part = (u32)__shfl_xor((int)mypk, 4);
    u32 pk = mypk | (part << 16);
    bool evenh = ((h4 & 1) == 0);
    if (evenh)
      AT_ST(hx + ((size_t)slotn * 32 + c) * 128 + (myrow << 3) + (mycol >> 1), pk);
    asm volatile("s_waitcnt vmcnt(0)" ::: "memory");
    if (lane == 0) AT_ST(myt + c * 4 + wave, (u32)(t + 2));
    if (seq && evenh)
      *(u32*)(seq + ((size_t)((grp * 16 + myrow) * 256 + t_eff)) * sstride +
              coloff + (c << 4) + mycol) = pk;
    if (hfin && t == 255)
      hfin[(size_t)(grp * 16 + myrow) * hstride + (c << 4) + mycol] = hh;
  }
}

// ---- tiny heads ----
__global__ void k_enc_head(const float* __restrict__ hcat, const float* __restrict__ W,
                           const float* __restrict__ b, float* __restrict__ zws,
                           float* __restrict__ zout) {
  int bi = blockIdx.x, j = threadIdx.x;
  const float* h = hcat + bi * 1024;
  const float* w = W + j * 1024;
  float s = b[j];
  for (int k = 0; k < 1024; ++k) s += h[k] * w[k];
  zws[bi * 128 + j] = s;
  zout[bi * 128 + j] = s;
}

__global__ void k_dec_head(const float* __restrict__ z, const float* __restrict__ W,
                           const float* __restrict__ b, float* __restrict__ h0d) {
  int bi = blockIdx.x, j = threadIdx.x;
  const float* zz = z + bi * 128;
  const float* w = W + j * 128;
  float s = b[j];
  for (int k = 0; k < 128; ++k) s += zz[k] * w[k];
  h0d[bi * 512 + j] = s;
}

extern "C" void kernel_launch(void* const* d_in, const int* in_sizes, int n_in,
                              void* d_out, int out_size, void* d_ws, size_t ws_size,
                              hipStream_t stream) {
  (void)in_sizes; (void)n_in; (void)out_size;
  const float* x        = (const float*)d_in[0];
  const float* e0f_Wih  = (const float*)d_in[1];
  const float* e0f_Whh  = (const float*)d_in[2];
  const float* e0f_b    = (const float*)d_in[3];
  const float* e0b_Wih  = (const float*)d_in[4];
  const float* e0b_Whh  = (const float*)d_in[5];
  const float* e0b_b    = (const float*)d_in[6];
  const float* e1f_Wih  = (const float*)d_in[7];
  const float* e1f_Whh  = (const float*)d_in[8];
  const float* e1f_b    = (const float*)d_in[9];
  const float* e1b_Wih  = (const float*)d_in[10];
  const float* e1b_Whh  = (const float*)d_in[11];
  const float* e1b_b    = (const float*)d_in[12];
  const float* enc_fc_W = (const float*)d_in[13];
  const float* enc_fc_b = (const float*)d_in[14];
  const float* dec_fc_W = (const float*)d_in[15];
  const float* dec_fc_b = (const float*)d_in[16];
  const float* start_tk = (const float*)d_in[17];
  const float* d0_Wih   = (const float*)d_in[18];
  const float* d0_Whh   = (const float*)d_in[19];
  const float* d0_b     = (const float*)d_in[20];
  const float* d1_Wih   = (const float*)d_in[21];
  const float* d1_Whh   = (const float*)d_in[22];
  const float* d1_b     = (const float*)d_in[23];
  const float* out_W    = (const float*)d_in[24];
  const float* out_b    = (const float*)d_in[25];

  uintptr_t base = (uintptr_t)d_ws;
  size_t off = 0;
  auto carve = [&](size_t bytes) -> void* {
    off = (off + 255) & ~(size_t)255;
    void* p = (void*)(base + off);
    off += bytes;
    return p;
  };
  u16* Ax     = (u16*)carve((size_t)2097152 * 2);
  u16* Axs    = (u16*)carve((size_t)2097152 * 2);
  u16* Wb_e0f = (u16*)carve((size_t)262144 * 2);
  u16* Wb_e0b = (u16*)carve((size_t)262144 * 2);
  u16* Wb_d0  = (u16*)carve((size_t)262144 * 2);
  u16* Wb_e1f = (u16*)carve((size_t)2097152 * 2);
  u16* Wb_e1b = (u16*)carve((size_t)2097152 * 2);
  u16* Wb_d1  = (u16*)carve((size_t)1048576 * 2);
  u16* Wb_out = (u16*)carve((size_t)65536 * 2);
  u16* Wh_e0f = (u16*)carve((size_t)1048576 * 2);
  u16* Wh_e0b = (u16*)carve((size_t)1048576 * 2);
  u16* Wh_e1f = (u16*)carve((size_t)1048576 * 2);
  u16* Wh_e1b = (u16*)carve((size_t)1048576 * 2);
  u16* Wh_d0  = (u16*)carve((size_t)1048576 * 2);
  u16* Wh_d1  = (u16*)carve((size_t)1048576 * 2);
  u16* slot0  = (u16*)carve((size_t)16384 * 2048 * 2);
  u16* slot1  = (u16*)carve((size_t)16384 * 2048 * 2);
  u16* l0     = (u16*)carve((size_t)33619968);  // l0 (32MB); later o1 + hxprod
  u16* hxring = (u16*)carve((size_t)524288);    // 8 chains x 4 slots x 32 w x 512B
  float* hcat = (float*)carve((size_t)65536 * 4);
  float* zws  = (float*)carve((size_t)8192 * 4);
  float* h0d  = (float*)carve((size_t)32768 * 4);
  u32* tags0  = (u32*)carve(4096);
  u32* tags1  = (u32*)carve(4096);
  u32* tags2  = (u32*)carve(4096);
  if (off > ws_size) return;

  u16* o1     = l0;                // alias: l0 dead after e1 gemms
  u16* hxprod = l0 + 8388608;      // +16MiB (u16 units)

  (void)hipMemsetAsync(tags0, 0, 12288, stream);

  k_prep_x<<<8192, 256, 0, stream>>>(x, start_tk, Ax, Axs, 2097152);
  {
    CvtJobs j{};
    const float* s[13] = {e0f_Wih, e0b_Wih, d0_Wih, e1f_Wih, e1b_Wih, d1_Wih, out_W,
                          e0f_Whh, e0b_Whh, e1f_Whh, e1b_Whh, d0_Whh, d1_Whh};
    u16* d[13] = {Wb_e0f, Wb_e0b, Wb_d0, Wb_e1f, Wb_e1b, Wb_d1, Wb_out,
                  Wh_e0f, Wh_e0b, Wh_e1f, Wh_e1b, Wh_d0, Wh_d1};
    int n[13] = {262144, 262144, 262144, 2097152, 2097152, 1048576, 65536,
                 1048576, 1048576, 1048576, 1048576, 1048576, 1048576};
    int acc = 0;
    for (int k = 0; k < 13; ++k) { j.src[k] = s[k]; j.dst[k] = d[k]; j.off[k] = acc; acc += n[k]; }
    j.off[13] = acc;
    k_cvt_all<<<(acc + 255) / 256, 256, 0, stream>>>(j, acc);
  }

  // encoder layer 0 projections + recurrence -> l0
  k_gemm_bt<<<dim3(128, 16), 256, 0, stream>>>(Ax, Wb_e0f, e0f_b, slot0, nullptr, 16384, 2048, 128, 0);
  k_gemm_bt<<<dim3(128, 16), 256, 0, stream>>>(Ax, Wb_e0b, e0b_b, slot1, nullptr, 16384, 2048, 128, 0);
  {
    Rec3 r{};
    for (int ch = 0; ch < 8; ++ch) {
      int dir2 = ch >> 2, g = ch & 3;
      r.xW[ch] = dir2 ? slot1 : slot0;
      r.Whh[ch] = dir2 ? Wh_e0b : Wh_e0f;
      r.Wih[ch] = nullptr; r.bias[ch] = nullptr; r.h0[ch] = nullptr;
      r.seq[ch] = l0; r.seqstride[ch] = 1024; r.coloff[ch] = dir2 ? 512 : 0;
      r.rev[ch] = dir2; r.hfin[ch] = nullptr; r.hfinstride[ch] = 0;
      r.grp[ch] = g; r.fused[ch] = 0; r.fullp[ch] = 0; r.prod[ch] = 0;
      r.hxc[ch] = hxring + (size_t)ch * 32768;
    }
    r.tags = tags0;
    k_rec3<<<256, 256, 0, stream>>>(r);
  }
  // encoder layer 1 projections + recurrence -> hcat
  k_gemm_bt<<<dim3(128, 16), 256, 0, stream>>>(l0, Wb_e1f, e1f_b, slot0, nullptr, 16384, 2048, 1024, 0);
  k_gemm_bt<<<dim3(128, 16), 256, 0, stream>>>(l0, Wb_e1b, e1b_b, slot1, nullptr, 16384, 2048, 1024, 0);
  {
    Rec3 r{};
    for (int ch = 0; ch < 8; ++ch) {
      int dir2 = ch >> 2, g = ch & 3;
      r.xW[ch] = dir2 ? slot1 : slot0;
      r.Whh[ch] = dir2 ? Wh_e1b : Wh_e1f;
      r.Wih[ch] = nullptr; r.bias[ch] = nullptr; r.h0[ch] = nullptr;
      r.seq[ch] = nullptr; r.seqstride[ch] = 0; r.coloff[ch] = 0;
      r.rev[ch] = dir2; r.hfin[ch] = hcat + (dir2 ? 512 : 0); r.hfinstride[ch] = 1024;
      r.grp[ch] = g; r.fused[ch] = 0; r.fullp[ch] = 0; r.prod[ch] = 0;
      r.hxc[ch] = hxring + (size_t)ch * 32768;
    }
    r.tags = tags1;
    k_rec3<<<256, 256, 0, stream>>>(r);
  }
  // bottleneck
  k_enc_head<<<64, 128, 0, stream>>>(hcat, enc_fc_W, enc_fc_b, zws, ((float*)d_out) + 2097152);
  k_dec_head<<<64, 512, 0, stream>>>(zws, dec_fc_W, dec_fc_b, h0d);
  // decoder: d0 projection, then fused d0||d1 recurrence -> o1
  k_gemm_bt<<<dim3(128, 16), 256, 0, stream>>>(Axs, Wb_d0, d0_b, slot0, nullptr, 16384, 2048, 128, 0);
  {
    Rec3 r{};
    for (int ch = 0; ch < 4; ++ch) {  // d0 chains: full-depth producers
      r.xW[ch] = slot0;
      r.Whh[ch] = Wh_d0;
      r.Wih[ch] = nullptr; r.bias[ch] = nullptr; r.h0[ch] = h0d;
      r.seq[ch] = nullptr; r.seqstride[ch] = 0; r.coloff[ch] = 0;
      r.rev[ch] = 0; r.hfin[ch] = nullptr; r.hfinstride[ch] = 0;
      r.grp[ch] = ch; r.fused[ch] = 0; r.fullp[ch] = 1; r.prod[ch] = 0;
      r.hxc[ch] = hxprod + (size_t)ch * 2105344;  // 257*32*256 u16
    }
    for (int ch = 4; ch < 8; ++ch) {  // d1 chains: fused consumers (own xW MFMA)
      r.xW[ch] = nullptr;
      r.Whh[ch] = Wh_d1;
      r.Wih[ch] = Wb_d1; r.bias[ch] = d1_b; r.h0[ch] = h0d;
      r.seq[ch] = o1; r.seqstride[ch] = 512; r.coloff[ch] = 0;
      r.rev[ch] = 0; r.hfin[ch] = nullptr; r.hfinstride[ch] = 0;
      r.grp[ch] = ch - 4; r.fused[ch] = 1; r.fullp[ch] = 0; r.prod[ch] = ch - 4;
      r.hxc[ch] = hxring + (size_t)ch * 32768;
    }
    r.tags = tags2;
    k_rec3<<<256, 256, 0, stream>>>(r);
  }
  // output projection + sigmoid
  k_gemm_bt<<<dim3(128, 1), 256, 0, stream>>>(o1, Wb_out, out_b, nullptr, (float*)d_out, 16384, 128, 512, 1);
}